// Round 2
// baseline (515.503 us; speedup 1.0000x reference)
//
#include <hip/hip_runtime.h>
#include <float.h>

// x: (B=64, w=512, h=48, M=64) fp32 -> out: (64, 16*6*64) fp32
// Uniform bins: row bin = r/32 (16 bins), col bin = c/8 (6 bins).
// One block per (b, iw): slice x[b, iw*32..iw*32+31, :, :] is contiguous 384 KB.
//
// Flat-stream indexing: slice viewed as 24576 float4s. Iter (q,k), thread t
// loads f = 768q + 256k + t  (q=0..31 row, k=0..2 phase). Every wave load is
// 64 consecutive float4s = 1 KB fully coalesced. For fixed t:
//   m4 = t & 15 (constant), c = (t>>4) + 16k  ->  ih = c>>3 = ih0-derived,
// so each thread keeps exactly 3 float4 accumulators (one per k).

#define BATCH 64
#define WDIM 512
#define HDIM 48
#define MDIM 64
#define PW 16
#define PH 6

__global__ __launch_bounds__(256) void dap_pool_kernel(const float* __restrict__ x,
                                                       float* __restrict__ out) {
    const int blk = blockIdx.x;       // 0..1023
    const int b   = blk >> 4;
    const int iw  = blk & 15;
    const int t   = threadIdx.x;      // 0..255

    const float4* base4 =
        (const float4*)(x + ((size_t)b * WDIM + (size_t)iw * 32) * (HDIM * MDIM));

    float4 acc[3];
#pragma unroll
    for (int k = 0; k < 3; ++k)
        acc[k] = make_float4(-FLT_MAX, -FLT_MAX, -FLT_MAX, -FLT_MAX);

    // main loop: 32 rows x 3 phases = 96 fully-coalesced loads/thread
#pragma unroll 4
    for (int q = 0; q < 32; ++q) {
#pragma unroll
        for (int k = 0; k < 3; ++k) {
            float4 v = base4[768 * q + 256 * k + t];
            acc[k].x = fmaxf(acc[k].x, v.x);
            acc[k].y = fmaxf(acc[k].y, v.y);
            acc[k].z = fmaxf(acc[k].z, v.z);
            acc[k].w = fmaxf(acc[k].w, v.w);
        }
    }

    // LDS: layout [k][t] of float4 -> 3*256*16 B = 12 KB
    __shared__ float4 lds[3 * 256];
#pragma unroll
    for (int k = 0; k < 3; ++k)
        lds[k * 256 + t] = acc[k];
    __syncthreads();

    // Output bin (ih, m4): k = ih>>1, contributing column-groups g = (ih&1)*8 .. +7,
    // source thread t' = g*16 + m4.
    if (t < PH * 16) {            // 96 threads
        const int ih = t >> 4;    // 0..5
        const int m4 = t & 15;    // 0..15
        const int k  = ih >> 1;
        const int gb = (ih & 1) * 8;
        float4 r0 = lds[k * 256 + (gb * 16 + m4)];
#pragma unroll
        for (int g = 1; g < 8; ++g) {
            float4 v = lds[k * 256 + ((gb + g) * 16 + m4)];
            r0.x = fmaxf(r0.x, v.x);
            r0.y = fmaxf(r0.y, v.y);
            r0.z = fmaxf(r0.z, v.z);
            r0.w = fmaxf(r0.w, v.w);
        }
        float4* o = (float4*)out;
        o[(size_t)b * (PW * PH * MDIM / 4) + iw * (PH * MDIM / 4) + ih * (MDIM / 4) + m4] = r0;
    }
}

extern "C" void kernel_launch(void* const* d_in, const int* in_sizes, int n_in,
                              void* d_out, int out_size, void* d_ws, size_t ws_size,
                              hipStream_t stream) {
    const float* x = (const float*)d_in[0];
    float* out = (float*)d_out;
    dim3 grid(BATCH * PW);   // (b, iw)
    dim3 block(256);
    dap_pool_kernel<<<grid, block, 0, stream>>>(x, out);
}